// Round 1
// baseline (1432.144 us; speedup 1.0000x reference)
//
#include <hip/hip_runtime.h>

#define CIN   8
#define COUT  16
#define HH    56
#define WW    56
#define SS    784                  // 28*28 symbolic vector per pixel
#define PLANE (HH * WW * SS)       // 2458624 floats per channel plane
#define ROW   (WW * SS)            // 43904
#define NF4   (HH * WW * (SS / 4)) // 614656 float4 units = 2401 * 256
#define SYM_OUT_SZ (COUT * PLANE)  // 39337984

typedef float f32x2 __attribute__((ext_vector_type(2)));
typedef float f32x4 __attribute__((ext_vector_type(4)));

#if defined(__has_builtin)
#if __has_builtin(__builtin_elementwise_fma)
#define PK_FMA(a, b, c) __builtin_elementwise_fma((a), (b), (c))
#endif
#endif
#ifndef PK_FMA
// -ffp-contract is on by default in hipcc: a*b+c contracts to fma
#define PK_FMA(a, b, c) ((a) * (b) + (c))
#endif

// Prep: transposed weight table in workspace.
// wtr[tap*32 + co]      = 0.5 * w[co][tap]
// wtr[tap*32 + 16 + co] = 0.5 * |w[co][tap]|
// (tap = ci*9 + dh*3 + dw). Uniform-address reads in the main kernel -> s_load.
__global__ __launch_bounds__(256) void ibp_prep_w(
    const float* __restrict__ wgt, float* __restrict__ wtr)
{
    const int i = blockIdx.x * 256 + threadIdx.x;
    if (i >= 72 * 16) return;
    const int tap = i >> 4, co = i & 15;
    const int ci = tap / 9, r = tap - ci * 9;
    const float w = wgt[(co * CIN + ci) * 9 + r];
    wtr[tap * 32 + co]      = 0.5f * w;
    wtr[tap * 32 + 16 + co] = 0.5f * fabsf(w);
}

// Main symbolic-bound conv.
//   lx_out = 0.5*(sum w*(lv+uv) + sum |w|*(lv-uv))
//   ux_out = 0.5*(sum w*(lv+uv) - sum |w|*(lv-uv))
// One thread owns one float4 of the 784-vector; 16 cout accumulated in regs
// as f32x2 pairs (v_pk_fma_f32). Weights come from workspace via scalar loads.
//
// Index space is remapped for L2 locality: (band, h, wi, j4) with 8-pixel-wide
// w-bands; blockIdx is swizzled so each XCD (blockIdx%8 round-robin) walks a
// contiguous h-run of one band -> the 3-row halo reuse stays in that XCD's L2.
__global__ __launch_bounds__(256, 3) void ibp_conv_sym(
    const float* __restrict__ lx, const float* __restrict__ ux,
    const float* __restrict__ wtr,
    float* __restrict__ lx_out, float* __restrict__ ux_out)
{
    const int tid = threadIdx.x;
    const int b   = blockIdx.x;
    // 2401 blocks: chunk 2400 into 8 runs of 300 (XCD k = b&7 gets v in [300k,300k+300))
    const int vblk = (b < 2400) ? ((b & 7) * 300 + (b >> 3)) : b;
    const int gv   = vblk * 256 + tid;      // virtual (band,h,wi,j4) linear index

    const int j4   = gv % 196;              // float4 index within pixel
    const int t    = gv / 196;              // (band*56 + h)*8 + wi
    const int wi   = t & 7;
    const int hb   = t >> 3;                // band*56 + h
    const int h    = hb % 56;
    const int band = hb / 56;
    const int w    = band * 8 + wi;

    const int pix  = h * WW + w;
    const int base = pix * SS + j4 * 4;     // float offset of this thread's float4

    const float* bl0 = lx + base;
    const float* bu0 = ux + base;

    // Accumulators: A = sum 0.5w*(l+u), B = sum 0.5|w|*(l-u); [co] x {elems 01, 23}
    f32x2 A0[COUT], A1[COUT], B0[COUT], B1[COUT];
    #pragma unroll
    for (int co = 0; co < COUT; ++co) {
        A0[co] = (f32x2)0.f; A1[co] = (f32x2)0.f;
        B0[co] = (f32x2)0.f; B1[co] = (f32x2)0.f;
    }

    for (int ci = 0; ci < CIN; ++ci) {
        const float* bl = bl0 + ci * PLANE;
        const float* bu = bu0 + ci * PLANE;
        #pragma unroll
        for (int dh = 0; dh < 3; ++dh) {
            const int ih = h + dh - 1;
            const bool vh = (unsigned)ih < (unsigned)HH;
            #pragma unroll
            for (int dw = 0; dw < 3; ++dw) {
                const int iw = w + dw - 1;
                const bool ok = vh && ((unsigned)iw < (unsigned)WW);
                const int off = (dh - 1) * ROW + (dw - 1) * SS;
                f32x4 lv = (f32x4)0.f, uv = (f32x4)0.f;
                if (ok) {
                    lv = *(const f32x4*)(bl + off);
                    uv = *(const f32x4*)(bu + off);
                }
                const f32x4 s = lv + uv;     // v_pk_add_f32
                const f32x4 d = lv - uv;
                const f32x2 s01 = __builtin_shufflevector(s, s, 0, 1);
                const f32x2 s23 = __builtin_shufflevector(s, s, 2, 3);
                const f32x2 d01 = __builtin_shufflevector(d, d, 0, 1);
                const f32x2 d23 = __builtin_shufflevector(d, d, 2, 3);

                const int tap = ci * 9 + dh * 3 + dw;
                const float* wp = wtr + tap * 32;   // uniform -> scalar loads
                #pragma unroll
                for (int co = 0; co < COUT; ++co) {
                    const float wa = wp[co];        // 0.5*w    (SGPR)
                    const float wb = wp[16 + co];   // 0.5*|w|  (SGPR)
                    const f32x2 wa2 = {wa, wa};
                    const f32x2 wb2 = {wb, wb};
                    A0[co] = PK_FMA(wa2, s01, A0[co]);
                    A1[co] = PK_FMA(wa2, s23, A1[co]);
                    B0[co] = PK_FMA(wb2, d01, B0[co]);
                    B1[co] = PK_FMA(wb2, d23, B1[co]);
                }
            }
        }
    }

    #pragma unroll
    for (int co = 0; co < COUT; ++co) {
        const f32x4 a = __builtin_shufflevector(A0[co], A1[co], 0, 1, 2, 3);
        const f32x4 bb = __builtin_shufflevector(B0[co], B1[co], 0, 1, 2, 3);
        const f32x4 lo = a + bb;
        const f32x4 uo = a - bb;
        *(f32x4*)(lx_out + (size_t)co * PLANE + base) = lo;
        *(f32x4*)(ux_out + (size_t)co * PLANE + base) = uo;
    }
}

// Constant-offset conv (tiny: 16*56*56 outputs each).
__global__ __launch_bounds__(256) void ibp_conv_const(
    const float* __restrict__ lc, const float* __restrict__ uc,
    const float* __restrict__ wgt, const float* __restrict__ bias,
    float* __restrict__ lc_out, float* __restrict__ uc_out)
{
    const int idx = blockIdx.x * 256 + threadIdx.x;
    if (idx >= COUT * HH * WW) return;
    const int co  = idx / (HH * WW);
    const int pix = idx - co * (HH * WW);
    const int h = pix / WW, w = pix - (pix / WW) * WW;

    float Aa = 0.f, Bb = 0.f;
    for (int ci = 0; ci < CIN; ++ci) {
        #pragma unroll
        for (int dh = 0; dh < 3; ++dh) {
            const int ih = h + dh - 1;
            if ((unsigned)ih >= (unsigned)HH) continue;
            #pragma unroll
            for (int dw = 0; dw < 3; ++dw) {
                const int iw = w + dw - 1;
                if ((unsigned)iw >= (unsigned)WW) continue;
                const float l = lc[(ci * HH + ih) * WW + iw];
                const float u = uc[(ci * HH + ih) * WW + iw];
                const float wv = wgt[((co * CIN + ci) * 3 + dh) * 3 + dw];
                Aa += wv * (l + u);
                Bb += fabsf(wv) * (l - u);
            }
        }
    }
    const float b = bias[co];
    lc_out[idx] = 0.5f * (Aa + Bb) + b;
    uc_out[idx] = 0.5f * (Aa - Bb) + b;
}

extern "C" void kernel_launch(void* const* d_in, const int* in_sizes, int n_in,
                              void* d_out, int out_size, void* d_ws, size_t ws_size,
                              hipStream_t stream) {
    const float* lx   = (const float*)d_in[0];
    const float* ux   = (const float*)d_in[1];
    const float* lc   = (const float*)d_in[2];
    const float* uc   = (const float*)d_in[3];
    const float* wgt  = (const float*)d_in[4];
    const float* bias = (const float*)d_in[5];

    float* out    = (float*)d_out;
    float* lx_out = out;
    float* ux_out = out + (size_t)SYM_OUT_SZ;
    float* lc_out = out + (size_t)2 * SYM_OUT_SZ;
    float* uc_out = lc_out + COUT * HH * WW;

    float* wtr = (float*)d_ws;   // 72*32 floats = 9216 B

    ibp_prep_w<<<(72 * 16 + 255) / 256, 256, 0, stream>>>(wgt, wtr);

    ibp_conv_sym<<<NF4 / 256, 256, 0, stream>>>(lx, ux, wtr, lx_out, ux_out);

    const int nconst = COUT * HH * WW;
    ibp_conv_const<<<(nconst + 255) / 256, 256, 0, stream>>>(
        lc, uc, wgt, bias, lc_out, uc_out);
}

// Round 2
// 647.527 us; speedup vs baseline: 2.2117x; 2.2117x over previous
//
#include <hip/hip_runtime.h>

#define CIN   8
#define COUT  16
#define HH    56
#define WW    56
#define SS    784                  // 28*28 symbolic vector per pixel
#define PLANE (HH * WW * SS)       // 2458624 floats per channel plane
#define ROW   (WW * SS)            // 43904
#define NF2   (HH * WW * (SS / 2)) // 1229312 float2 units = 4802 * 256
#define SYM_OUT_SZ (COUT * PLANE)  // 39337984

typedef float f32x2 __attribute__((ext_vector_type(2)));

#if defined(__has_builtin)
#if __has_builtin(__builtin_elementwise_fma)
#define PK_FMA(a, b, c) __builtin_elementwise_fma((a), (b), (c))
#endif
#endif
#ifndef PK_FMA
#define PK_FMA(a, b, c) ((a) * (b) + (c))
#endif

// Prep: transposed weight table in workspace.
// wtr[tap*32 + co]      = 0.5 * w[co][tap]
// wtr[tap*32 + 16 + co] = 0.5 * |w[co][tap]|
// (tap = ci*9 + dh*3 + dw). Uniform-address reads in the main kernel -> s_load.
__global__ __launch_bounds__(256) void ibp_prep_w(
    const float* __restrict__ wgt, float* __restrict__ wtr)
{
    const int i = blockIdx.x * 256 + threadIdx.x;
    if (i >= 72 * 16) return;
    const int tap = i >> 4, co = i & 15;
    const int ci = tap / 9, r = tap - ci * 9;
    const float w = wgt[(co * CIN + ci) * 9 + r];
    wtr[tap * 32 + co]      = 0.5f * w;
    wtr[tap * 32 + 16 + co] = 0.5f * fabsf(w);
}

// Main symbolic-bound conv.
//   lx_out = 0.5*(sum w*(lv+uv) + sum |w|*(lv-uv))
//   ux_out = 0.5*(sum w*(lv+uv) - sum |w|*(lv-uv))
// One thread owns ONE float2 of the 784-vector (halves accumulator state vs
// float4 -> ~64 acc VGPRs -> ~4 waves/SIMD without launch-bounds forcing).
// Weights come from workspace via uniform scalar loads (no LDS).
//
// Index space remapped for L2 locality: (band, h, wi, j2) with 8-pixel-wide
// w-bands; blockIdx chunked so each XCD (hw round-robins blockIdx%8) walks a
// contiguous h-run of one band -> 3-row halo reuse stays in that XCD's L2.
__global__ __launch_bounds__(256) void ibp_conv_sym(
    const float* __restrict__ lx, const float* __restrict__ ux,
    const float* __restrict__ wtr,
    float* __restrict__ lx_out, float* __restrict__ ux_out)
{
    const int tid = threadIdx.x;
    const int b   = blockIdx.x;
    // 4802 blocks: chunk 4800 into 8 runs of 600 (XCD k = b&7 gets v in [600k,600k+600))
    const int vblk = (b < 4800) ? ((b & 7) * 600 + (b >> 3)) : b;
    const int gv   = vblk * 256 + tid;      // virtual (band,h,wi,j2) linear index

    const int j2   = gv % 392;              // float2 index within pixel
    const int t    = gv / 392;              // (band*56 + h)*8 + wi
    const int wi   = t & 7;
    const int hb   = t >> 3;                // band*56 + h
    const int h    = hb % 56;
    const int band = hb / 56;
    const int w    = band * 8 + wi;

    const int pix  = h * WW + w;
    const int base = pix * SS + j2 * 2;     // float offset of this thread's float2

    const float* bl0 = lx + base;
    const float* bu0 = ux + base;

    // Accumulators: A = sum 0.5w*(l+u), B = sum 0.5|w|*(l-u); one f32x2 per cout
    f32x2 A[COUT], B[COUT];
    #pragma unroll
    for (int co = 0; co < COUT; ++co) {
        A[co] = (f32x2)0.f;
        B[co] = (f32x2)0.f;
    }

    for (int ci = 0; ci < CIN; ++ci) {
        const float* bl = bl0 + ci * PLANE;
        const float* bu = bu0 + ci * PLANE;
        #pragma unroll
        for (int dh = 0; dh < 3; ++dh) {
            const int ih = h + dh - 1;
            const bool vh = (unsigned)ih < (unsigned)HH;
            #pragma unroll
            for (int dw = 0; dw < 3; ++dw) {
                const int iw = w + dw - 1;
                const bool ok = vh && ((unsigned)iw < (unsigned)WW);
                const int off = (dh - 1) * ROW + (dw - 1) * SS;
                f32x2 lv = (f32x2)0.f, uv = (f32x2)0.f;
                if (ok) {
                    lv = *(const f32x2*)(bl + off);
                    uv = *(const f32x2*)(bu + off);
                }
                const f32x2 s = lv + uv;     // v_pk_add_f32
                const f32x2 d = lv - uv;

                const int tap = ci * 9 + dh * 3 + dw;
                const float* wp = wtr + tap * 32;   // uniform -> scalar loads
                #pragma unroll
                for (int co = 0; co < COUT; ++co) {
                    const float wa = wp[co];        // 0.5*w    (SGPR)
                    const float wb = wp[16 + co];   // 0.5*|w|  (SGPR)
                    const f32x2 wa2 = {wa, wa};
                    const f32x2 wb2 = {wb, wb};
                    A[co] = PK_FMA(wa2, s, A[co]);
                    B[co] = PK_FMA(wb2, d, B[co]);
                }
            }
        }
    }

    #pragma unroll
    for (int co = 0; co < COUT; ++co) {
        const f32x2 lo = A[co] + B[co];
        const f32x2 uo = A[co] - B[co];
        // Outputs are never re-read: nontemporal keeps 307 MB of writes from
        // evicting the L3-resident inputs.
        __builtin_nontemporal_store(lo, (f32x2*)(lx_out + (size_t)co * PLANE + base));
        __builtin_nontemporal_store(uo, (f32x2*)(ux_out + (size_t)co * PLANE + base));
    }
}

// Constant-offset conv (tiny: 16*56*56 outputs each).
__global__ __launch_bounds__(256) void ibp_conv_const(
    const float* __restrict__ lc, const float* __restrict__ uc,
    const float* __restrict__ wgt, const float* __restrict__ bias,
    float* __restrict__ lc_out, float* __restrict__ uc_out)
{
    const int idx = blockIdx.x * 256 + threadIdx.x;
    if (idx >= COUT * HH * WW) return;
    const int co  = idx / (HH * WW);
    const int pix = idx - co * (HH * WW);
    const int h = pix / WW, w = pix - (pix / WW) * WW;

    float Aa = 0.f, Bb = 0.f;
    for (int ci = 0; ci < CIN; ++ci) {
        #pragma unroll
        for (int dh = 0; dh < 3; ++dh) {
            const int ih = h + dh - 1;
            if ((unsigned)ih >= (unsigned)HH) continue;
            #pragma unroll
            for (int dw = 0; dw < 3; ++dw) {
                const int iw = w + dw - 1;
                if ((unsigned)iw >= (unsigned)WW) continue;
                const float l = lc[(ci * HH + ih) * WW + iw];
                const float u = uc[(ci * HH + ih) * WW + iw];
                const float wv = wgt[((co * CIN + ci) * 3 + dh) * 3 + dw];
                Aa += wv * (l + u);
                Bb += fabsf(wv) * (l - u);
            }
        }
    }
    const float b = bias[co];
    lc_out[idx] = 0.5f * (Aa + Bb) + b;
    uc_out[idx] = 0.5f * (Aa - Bb) + b;
}

extern "C" void kernel_launch(void* const* d_in, const int* in_sizes, int n_in,
                              void* d_out, int out_size, void* d_ws, size_t ws_size,
                              hipStream_t stream) {
    const float* lx   = (const float*)d_in[0];
    const float* ux   = (const float*)d_in[1];
    const float* lc   = (const float*)d_in[2];
    const float* uc   = (const float*)d_in[3];
    const float* wgt  = (const float*)d_in[4];
    const float* bias = (const float*)d_in[5];

    float* out    = (float*)d_out;
    float* lx_out = out;
    float* ux_out = out + (size_t)SYM_OUT_SZ;
    float* lc_out = out + (size_t)2 * SYM_OUT_SZ;
    float* uc_out = lc_out + COUT * HH * WW;

    float* wtr = (float*)d_ws;   // 72*32 floats = 9216 B

    ibp_prep_w<<<(72 * 16 + 255) / 256, 256, 0, stream>>>(wgt, wtr);

    ibp_conv_sym<<<NF2 / 256, 256, 0, stream>>>(lx, ux, wtr, lx_out, ux_out);

    const int nconst = COUT * HH * WW;
    ibp_conv_const<<<(nconst + 255) / 256, 256, 0, stream>>>(
        lc, uc, wgt, bias, lc_out, uc_out);
}